// Round 1
// 207.417 us; speedup vs baseline: 1.0351x; 1.0351x over previous
//
#include <hip/hip_runtime.h>
#include <stdint.h>

// Exact fp32 reproduction of the numpy reference requires no FMA contraction
// and identical association order everywhere below.
#pragma clang fp contract(off)

#define B_    4
#define NV_   6890
#define NF_   27552     // 2*13776
#define IMG_  128
#define UV_   256
#define NPIX  (IMG_*IMG_)

#define TS_     8                 // tile edge in pixels
#define TPB_    (IMG_/TS_)        // 16 tiles per row/col
#define NTILE_  (TPB_*TPB_)       // 256 tiles per batch
#define NBIN_   (B_*NTILE_)       // 1024 bins
#define LIST_CAP (2*1024*1024)    // entries (8 MB); measured need ~1.2M
#define MAXC_   (LIST_CAP/256 + NBIN_)  // 9216: hard bound on work chunks

// ---------------------------------------------------------------- projection
__global__ void __launch_bounds__(256) project_k(
    const float* __restrict__ cam, const float* __restrict__ verts,
    float* __restrict__ vp) {
  int idx = blockIdx.x * 256 + threadIdx.x;
  if (idx >= B_ * NV_) return;
  int b = idx / NV_;
  float c0 = cam[b * 3 + 0], c1 = cam[b * 3 + 1], c2 = cam[b * 3 + 2];
  float tz = 500.0f / (64.0f * c0);                  // FLENGTH/(p*cam0), p=64
  const float* src = verts + (size_t)idx * 3;
  float* dst = vp + (size_t)idx * 3;
  dst[0] = c0 * (src[0] + c1);
  dst[1] = c0 * (src[1] + c2);
  dst[2] = src[2] + tz;
}

// ------------------------------------------------------------------- binning
// Backface cull (area_c < -1e-3, bit-safe bound proven in R1) + bbox(+-1px)
// -> range of overlapped 8x8 tiles. +-1 px margin: accepted pixels can exceed
// the fp bbox by <~1e-3 px only (fp error of w-tests ~1e-5 NDC).
__device__ __forceinline__ int face_tiles(
    const float* __restrict__ vp, const int* __restrict__ faces, int b, int f,
    int& tx0, int& tx1, int& ty0, int& ty1) {
  int ia = faces[f * 3 + 0], ib = faces[f * 3 + 1], ic = faces[f * 3 + 2];
  const float* vb = vp + (size_t)b * NV_ * 3;
  float x0 = vb[ia * 3 + 0], y0 = vb[ia * 3 + 1];
  float x1 = vb[ib * 3 + 0], y1 = vb[ib * 3 + 1];
  float x2 = vb[ic * 3 + 0], y2 = vb[ic * 3 + 1];
  float area_c = (x1 - x0) * (y2 - y0) - (y1 - y0) * (x2 - x0);
  if (area_c < -1e-3f) return 0;
  float xmn = fminf(x0, fminf(x1, x2)), xmx = fmaxf(x0, fmaxf(x1, x2));
  float ymn = fminf(y0, fminf(y1, y2)), ymx = fmaxf(y0, fmaxf(y1, y2));
  int jlo = (int)floorf((xmn + 1.0f) * 64.0f - 0.5f) - 1;
  int jhi = (int)ceilf ((xmx + 1.0f) * 64.0f - 0.5f) + 1;
  int ilo = (int)floorf((1.0f - ymx) * 64.0f - 0.5f) - 1;
  int ihi = (int)ceilf ((1.0f - ymn) * 64.0f - 0.5f) + 1;
  if (jhi < 0 || ihi < 0 || jlo > IMG_ - 1 || ilo > IMG_ - 1) return 0;
  jlo = max(jlo, 0); ilo = max(ilo, 0);
  jhi = min(jhi, IMG_ - 1); ihi = min(ihi, IMG_ - 1);
  tx0 = jlo >> 3; tx1 = jhi >> 3; ty0 = ilo >> 3; ty1 = ihi >> 3;
  return 1;
}

// Block-local LDS count aggregation (R5-validated). Also caches the packed
// tile rect per (b,f) so bin_fill_k skips recomputing face_tiles.
__global__ void __launch_bounds__(256) bin_count_k(
    const float* __restrict__ vp, const int* __restrict__ faces,
    int* __restrict__ cnt, int* __restrict__ rects) {
  __shared__ int scnt[NTILE_];
  int f = blockIdx.x * 256 + threadIdx.x;
  int b = blockIdx.y;
  scnt[threadIdx.x] = 0;
  __syncthreads();
  int tx0, tx1, ty0, ty1;
  int valid = (f < NF_) ? face_tiles(vp, faces, b, f, tx0, tx1, ty0, ty1) : 0;
  if (f < NF_)
    rects[(size_t)b * NF_ + f] =
        valid ? (tx0 | (tx1 << 4) | (ty0 << 8) | (ty1 << 12) | (1 << 16)) : 0;
  if (valid)
    for (int ty = ty0; ty <= ty1; ++ty)
      for (int tx = tx0; tx <= tx1; ++tx)
        atomicAdd(&scnt[ty * TPB_ + tx], 1);
  __syncthreads();
  int t = threadIdx.x;
  int v = scnt[t];
  if (v > 0) atomicAdd(&cnt[b * NTILE_ + t], v);
}

// Scan bin counts -> offsets; also scan chunk counts (ceil(cnt/256)) into a
// flat balanced work list of (bin, chunk) pairs; total chunk count -> nC.
__global__ void __launch_bounds__(1024) scan_k(
    const int* __restrict__ cnt, int* __restrict__ off, int* __restrict__ cur,
    int* __restrict__ work, int* __restrict__ nC) {
  __shared__ int sm[NBIN_];
  int t = threadIdx.x;
  int v = cnt[t];
  sm[t] = v;
  __syncthreads();
  for (int d = 1; d < NBIN_; d <<= 1) {
    int u = (t >= d) ? sm[t - d] : 0;
    __syncthreads();
    sm[t] += u;
    __syncthreads();
  }
  int o = sm[t] - v;
  off[t] = o;
  cur[t] = o;
  int nch = (v + 255) >> 8;
  __syncthreads();
  sm[t] = nch;
  __syncthreads();
  for (int d = 1; d < NBIN_; d <<= 1) {
    int u = (t >= d) ? sm[t - d] : 0;
    __syncthreads();
    sm[t] += u;
    __syncthreads();
  }
  int cb = sm[t] - nch;
  if (t == NBIN_ - 1) nC[0] = sm[t];
  for (int c = 0; c < nch; ++c) work[cb + c] = t | (c << 10);
}

// Block-local fill (R5-validated), using the cached rects from bin_count_k.
__global__ void __launch_bounds__(256) bin_fill_k(
    const int* __restrict__ rects, int* __restrict__ cur,
    int* __restrict__ list) {
  __shared__ int scnt[NTILE_];
  __shared__ int sbase[NTILE_];
  int f = blockIdx.x * 256 + threadIdx.x;
  int b = blockIdx.y;
  scnt[threadIdx.x] = 0;
  __syncthreads();
  int rv = (f < NF_) ? rects[(size_t)b * NF_ + f] : 0;
  int valid = rv >> 16;
  int tx0 = rv & 15, tx1 = (rv >> 4) & 15;
  int ty0 = (rv >> 8) & 15, ty1 = (rv >> 12) & 15;
  if (valid)
    for (int ty = ty0; ty <= ty1; ++ty)
      for (int tx = tx0; tx <= tx1; ++tx)
        atomicAdd(&scnt[ty * TPB_ + tx], 1);
  __syncthreads();
  int t = threadIdx.x;
  int v = scnt[t];
  if (v > 0) sbase[t] = atomicAdd(&cur[b * NTILE_ + t], v);
  __syncthreads();
  scnt[t] = 0;            // reuse as per-bin rank counter
  __syncthreads();
  if (valid)
    for (int ty = ty0; ty <= ty1; ++ty)
      for (int tx = tx0; tx <= tx1; ++tx) {
        int bin = ty * TPB_ + tx;
        int r = atomicAdd(&scnt[bin], 1);
        int slot = sbase[bin] + r;
        if (slot < LIST_CAP) list[slot] = f;
      }
}

// ---------------------------------------------------------------- rasterizer
// One 256-thread block per work chunk (bin, 256 faces). Inside test
// `area>0 && !(min3(w)<0)` == reference's post-divide b>=0 (R3-R5 validated,
// absmax 0.0; min3 preserves -0 semantics since !(-0<0)==true).
//
// R6: approximate-depth gate. zpa = (area*z0z1z2)*rcp(w0*z1z2+w1*z0z2+w2*z0z1)
// has relative error <= ~2e-5 (positive sums, z>0, v_rcp ~1ulp). The exact
// reference divide chain (7 IEEE divides) runs ONLY if !(zpa > kb_z*1.001):
// skip implies zp > kb_z strictly, so the winning key is bit-identical.
//
// R7 (this round): the loop is VALU-issue-bound and almost all iterations are
// provably useless. Three exact-by-construction prunes:
//  (a) per-wave bitonic sort of the 64 staged faces by truncated face zmin
//      (ascending). A sort is a pure permutation -> result unaffected.
//  (b) sorted-prefix break: zp(face,pixel) >= zmin(face) >= zmin_trunc, and
//      the staged zmin_trunc sequence is nondecreasing, so when
//      __all(zmn[q] > kbz) every remaining face satisfies zp > kbz strictly
//      (NaN kbz => never breaks). kbz is always the z of a REAL candidate
//      (seed or local accept), so skipped faces lose the final atomicMin.
//  (c) z-buffer seeding: atomicMin(zkey, ~0ull) is a device-scope no-op RMW
//      -> coherent, untorn snapshot of the current best key. Only the hi-32
//      z word is used (never merged into kb, so a concurrent writer can't
//      corrupt the (z,fid) pairing). zkey only decreases, so pruning against
//      it is exact. Later-scheduled chunks (most of the ~5700) see a nearly
//      final z-buffer and break after a few iterations.
__global__ void __launch_bounds__(256) raster_k(
    const float* __restrict__ vp, const int* __restrict__ faces,
    const int* __restrict__ list, const int* __restrict__ cnt,
    const int* __restrict__ off, const int* __restrict__ work,
    const int* __restrict__ nC, unsigned long long* __restrict__ zkey) {
  __shared__ float4 fd[4][5][64];   // [wave][field][rank]: 8-way write banks
  __shared__ unsigned long long mg[4][64];
  __shared__ float zmn[4][64];      // truncated zmin, ascending per wave
  __shared__ unsigned sdz[64];      // seeded z (hi word of zkey) per pixel
  int bid = blockIdx.x;
  if (bid >= nC[0]) return;                       // block-uniform exit
  int wkv = work[bid];
  int bin = wkv & (NBIN_ - 1);
  int chunk = wkv >> 10;
  int b = bin >> 8;
  int t = bin & 255;
  int tyT = t >> 4, txT = t & 15;
  int ws = threadIdx.x >> 6, lane = threadIdx.x & 63;
  int pi = tyT * TS_ + (lane >> 3);
  int pj = txT * TS_ + (lane & 7);
  // exact: (2j+1)/128-1 and 1-(2i+1)/128 are multiples of 2^-7 in [-1,1]
  float px = fmaf((float)pj, 0.015625f, -0.9921875f);
  float py = fmaf((float)pi, -0.015625f, 0.9921875f);

  int n = cnt[bin];
  int seg = (chunk << 8) + (ws << 6);
  int base0 = off[bin] + seg;
  int mw = min(n - seg, 64);
  mw = max(mw, 0);

  // (c) coherent z-buffer snapshot, one atomic per pixel per block.
  if (threadIdx.x < 64) {
    unsigned long long s =
        atomicMin(zkey + (size_t)b * NPIX + pi * IMG_ + pj, ~0ull);
    sdz[threadIdx.x] = (unsigned)(s >> 32);
  }

  unsigned skey = 0xFFFFFFC0u | (unsigned)lane;   // inactive lanes sort last
  float ztr = 0.0f;
  int fid = 0;
  float X0 = 0, Y0 = 0, Z0 = 0, X1 = 0, Y1 = 0, Z1 = 0, X2 = 0, Y2 = 0,
        Z2 = 0;
  if (lane < mw) {
    fid = list[base0 + lane];
    int ia = faces[fid * 3 + 0], ib = faces[fid * 3 + 1],
        ic = faces[fid * 3 + 2];
    const float* vb = vp + (size_t)b * NV_ * 3;
    X0 = vb[ia * 3 + 0]; Y0 = vb[ia * 3 + 1]; Z0 = vb[ia * 3 + 2];
    X1 = vb[ib * 3 + 0]; Y1 = vb[ib * 3 + 1]; Z1 = vb[ib * 3 + 2];
    X2 = vb[ic * 3 + 0]; Y2 = vb[ic * 3 + 1]; Z2 = vb[ic * 3 + 2];
    float zmin = fminf(Z0, fminf(Z1, Z2));
    unsigned zb = __float_as_uint(zmin) & 0xFFFFFFC0u;  // key: z | src lane
    skey = zb | (unsigned)lane;
    ztr = __uint_as_float(zb);   // <= zmin <= zp: safe break reference
  }
  int rank = lane;
  int dosort = (mw > 16);        // sort overhead not worth it for tiny waves
  if (dosort) {
    // (a) 64-lane bitonic sort (ascending); keys distinct (lane in low bits)
    for (int k = 2; k <= 64; k <<= 1)
      for (int j = k >> 1; j > 0; j >>= 1) {
        unsigned o = (unsigned)__shfl_xor((int)skey, j, 64);
        unsigned mn = skey < o ? skey : o;
        unsigned mx = skey < o ? o : skey;
        skey = (((lane & k) == 0) == ((lane & j) == 0)) ? mn : mx;
      }
    // inverse permutation: sorted lane L pushes its position to source lane
    rank = __builtin_amdgcn_ds_permute(((int)(skey & 63u)) << 2, lane);
  }
  if (lane < mw) {
    fd[ws][0][rank] = make_float4(X2 - X1, Y2 - Y1, X1, Y1);   // d21, v1
    fd[ws][1][rank] = make_float4(X0 - X2, Y0 - Y2, X2, Y2);   // d02, v2
    fd[ws][2][rank] = make_float4(X1 - X0, Y1 - Y0, X0, Y0);   // d10, v0
    fd[ws][3][rank] = make_float4(Z0, Z1, Z2, __int_as_float(fid));
    fd[ws][4][rank] =
        make_float4(Z1 * Z2, Z0 * Z2, Z0 * Z1, Z0 * Z1 * Z2);  // approx prods
    zmn[ws][rank] = ztr;
  }
  __syncthreads();

  unsigned long long kb = ~0ull;
  float kbz = __uint_as_float(sdz[lane]);          // NaN if pixel still empty
  float gate = kbz * 1.001f;                       // NaN -> first accept exact
  for (int q = 0; q < mw; ++q) {
    // (b) all remaining faces strictly deeper than a real candidate -> stop
    if (dosort && __all(zmn[ws][q] > kbz)) break;
    float4 A = fd[ws][0][q];
    float4 Bv = fd[ws][1][q];
    float4 Cv = fd[ws][2][q];
    float w0 = A.x * (py - A.w) - A.y * (px - A.z);
    float w1 = Bv.x * (py - Bv.w) - Bv.y * (px - Bv.z);
    float w2 = Cv.x * (py - Cv.w) - Cv.y * (px - Cv.z);
    float area = (w0 + w1) + w2;
    float mn = fminf(w0, fminf(w1, w2));
    if (area > 0.0f && !(mn < 0.0f)) {
      float4 P = fd[ws][4][q];
      float num = (w0 * P.x + w1 * P.y) + w2 * P.z;   // approx: any order
      float zpa = (area * P.w) * __builtin_amdgcn_rcpf(num);
      if (!(zpa > gate)) {                            // NaN-safe gate
        float4 Z = fd[ws][3][q];
        float b0 = w0 / area, b1 = w1 / area, b2 = w2 / area;
        float invz = (b0 / Z.x + b1 / Z.y) + b2 / Z.z;
        float zp = 1.0f / (invz == 0.0f ? 1.0f : invz);
        if (zp > 0.1f && zp < 25.0f) {
          unsigned long long key =
              ((unsigned long long)__float_as_uint(zp) << 32) |
              (unsigned int)__float_as_int(Z.w);
          if (key < kb) {
            kb = key;
            float zacc = __uint_as_float((unsigned)(kb >> 32));
            kbz = !(zacc >= kbz) ? zacc : kbz;        // NaN-safe running min
            gate = kbz * 1.001f;
          }
        }
      }
    }
  }

  mg[ws][lane] = kb;
  __syncthreads();
  if (ws == 0) {
    unsigned long long k0 = mg[0][lane];
    unsigned long long k1 = mg[1][lane];
    unsigned long long k2 = mg[2][lane];
    unsigned long long k3 = mg[3][lane];
    k0 = k1 < k0 ? k1 : k0;
    k2 = k3 < k2 ? k3 : k2;
    k0 = k2 < k0 ? k2 : k0;
    if (k0 != ~0ull)
      atomicMin(zkey + (size_t)b * NPIX + pi * IMG_ + pj, k0);
  }
}

// ------------------------------------------------------------------- shading
#define TAP(ty, tx, wexpr)                                                   \
  {                                                                          \
    int ty_ = (ty), tx_ = (tx);                                              \
    float w_ = (wexpr);                                                      \
    float valid_ =                                                           \
        (tx_ >= 0 && tx_ < UV_ && ty_ >= 0 && ty_ < UV_) ? 1.0f : 0.0f;      \
    float wv_ = w_ * valid_;                                                 \
    int cy_ = min(max(ty_, 0), UV_ - 1), cx_ = min(max(tx_, 0), UV_ - 1);    \
    int o_ = cy_ * UV_ + cx_;                                                \
    cr = cr + img[o_] * wv_;                                                 \
    cg = cg + img[UV_ * UV_ + o_] * wv_;                                     \
    cb = cb + img[2 * UV_ * UV_ + o_] * wv_;                                 \
  }

__global__ void __launch_bounds__(256) shade_k(
    const float* __restrict__ vp, const int* __restrict__ faces,
    const float* __restrict__ uv, const float* __restrict__ samp,
    const unsigned long long* __restrict__ zkey, float* __restrict__ out) {
  int idx = blockIdx.x * 256 + threadIdx.x;
  if (idx >= B_ * NPIX) return;
  int b = idx / NPIX;
  int p = idx - b * NPIX;
  int ii = p / IMG_;
  int jj = p - ii * IMG_;

  unsigned long long key = zkey[idx];
  float cr = 0.0f, cg = 0.0f, cb = 0.0f;
  if (key != 0xFFFFFFFFFFFFFFFFull) {
    int f = (int)(key & 0xFFFFFFFFull);
    int ia = faces[f * 3 + 0], ib = faces[f * 3 + 1], ic = faces[f * 3 + 2];
    const float* vb = vp + (size_t)b * NV_ * 3;
    float x0 = vb[ia * 3 + 0], y0 = vb[ia * 3 + 1];
    float x1 = vb[ib * 3 + 0], y1 = vb[ib * 3 + 1];
    float x2 = vb[ic * 3 + 0], y2 = vb[ic * 3 + 1];
    float px = (float)(2 * jj + 1) / 128.0f - 1.0f;
    float py = 1.0f - (float)(2 * ii + 1) / 128.0f;
    float w0 = (x2 - x1) * (py - y1) - (y2 - y1) * (px - x1);
    float w1 = (x0 - x2) * (py - y2) - (y0 - y2) * (px - x2);
    float w2 = (x1 - x0) * (py - y0) - (y1 - y0) * (px - x0);
    float area = (w0 + w1) + w2;
    float s = (area == 0.0f) ? 1.0f : area;
    float b0 = w0 / s, b1 = w1 / s;
    int t0 = min(max((int)floorf(b0 * 3.0f), 0), 2);
    int t1 = min(max((int)floorf(b1 * 3.0f), 0), 2);

    // lazy texture fetch: textures[b,f,t0,t1,*,c] == bilinear(uv_imgs[b],
    // sampler[f, t0*3+t1]); lighting multiplier is exactly 1.0 -> skipped.
    const float* g = samp + ((size_t)f * 9 + (size_t)(t0 * 3 + t1)) * 2;
    float gx = g[0], gy = g[1];
    float x = (gx + 1.0f) * 128.0f - 0.5f;   // (g+1)*(W*0.5)-0.5, W=256
    float y = (gy + 1.0f) * 128.0f - 0.5f;
    float x0f = floorf(x), y0f = floorf(y);
    float wx = x - x0f, wy = y - y0f;
    int xi = (int)x0f, yi = (int)y0f;
    float omwx = 1.0f - wx, omwy = 1.0f - wy;
    const float* img = uv + (size_t)b * 3 * UV_ * UV_;
    // reference accumulation order: (y0,x0)+(y0,x0+1)+(y0+1,x0)+(y0+1,x0+1)
    TAP(yi,     xi,     omwx * omwy)
    TAP(yi,     xi + 1, wx * omwy)
    TAP(yi + 1, xi,     omwx * wy)
    TAP(yi + 1, xi + 1, wx * wy)
  }
  out[((size_t)b * 3 + 0) * NPIX + p] = cr;
  out[((size_t)b * 3 + 1) * NPIX + p] = cg;
  out[((size_t)b * 3 + 2) * NPIX + p] = cb;
}

// ------------------------------------------------------------------- launch
extern "C" void kernel_launch(void* const* d_in, const int* in_sizes, int n_in,
                              void* d_out, int out_size, void* d_ws,
                              size_t ws_size, hipStream_t stream) {
  const float* cam   = (const float*)d_in[0];
  const float* verts = (const float*)d_in[1];
  const float* uv    = (const float*)d_in[2];
  const float* samp  = (const float*)d_in[3];
  const int*   faces = (const int*)d_in[4];

  char* ws = (char*)d_ws;
  size_t o = 0;
  unsigned long long* zkey = (unsigned long long*)(ws + o);
  o += (size_t)B_ * NPIX * 8;                                   // 512 KB
  float* vp = (float*)(ws + o);
  o += ((size_t)B_ * NV_ * 3 * 4 + 1023) & ~1023ull;            // ~331 KB
  int* cnt   = (int*)(ws + o); o += NBIN_ * 4;
  int* offs  = (int*)(ws + o); o += NBIN_ * 4;
  int* cur   = (int*)(ws + o); o += NBIN_ * 4;
  int* nC    = (int*)(ws + o); o += 1024;
  int* work  = (int*)(ws + o); o += (size_t)MAXC_ * 4;          // 36 KB
  int* rects = (int*)(ws + o); o += (size_t)B_ * NF_ * 4;       // 440 KB
  int* list  = (int*)(ws + o);                                  // 8 MB

  hipMemsetAsync(zkey, 0xFF, (size_t)B_ * NPIX * 8, stream);
  hipMemsetAsync(cnt, 0, NBIN_ * 4, stream);
  project_k<<<(B_ * NV_ + 255) / 256, 256, 0, stream>>>(cam, verts, vp);
  dim3 bgrid((NF_ + 255) / 256, B_);
  bin_count_k<<<bgrid, 256, 0, stream>>>(vp, faces, cnt, rects);
  scan_k<<<1, NBIN_, 0, stream>>>(cnt, offs, cur, work, nC);
  bin_fill_k<<<bgrid, 256, 0, stream>>>(rects, cur, list);
  raster_k<<<MAXC_, 256, 0, stream>>>(vp, faces, list, cnt, offs, work, nC,
                                      zkey);
  shade_k<<<(B_ * NPIX + 255) / 256, 256, 0, stream>>>(vp, faces, uv, samp,
                                                       zkey, (float*)d_out);
}